// Round 8
// baseline (464.022 us; speedup 1.0000x reference)
//
#include <hip/hip_runtime.h>
#include <hip/hip_bf16.h>

typedef __attribute__((ext_vector_type(8))) short short8;
typedef __attribute__((ext_vector_type(4))) short short4_t;
typedef __attribute__((ext_vector_type(4))) float f32x4;

__device__ __forceinline__ short bfc(float f) {
  return __builtin_bit_cast(short, __float2bfloat16(f));
}
__device__ __forceinline__ float bf2f(short s) {
  unsigned u = ((unsigned)(unsigned short)s) << 16;
  return __builtin_bit_cast(float, u);
}

__device__ __forceinline__ void gll16(const void* g, void* l) {
  __builtin_amdgcn_global_load_lds((const __attribute__((address_space(1))) unsigned int*)g,
                                   (__attribute__((address_space(3))) unsigned int*)l,
                                   16, 0, 0);
}

// ---------------- fp32 -> bf16 convert ----------------
__global__ void cvt_bf16(const float* __restrict__ in, short* __restrict__ out, int n8) {
  int i = blockIdx.x * blockDim.x + threadIdx.x;
  int stride = gridDim.x * blockDim.x;
  for (; i < n8; i += stride) {
    float4 a = ((const float4*)in)[2 * i];
    float4 b = ((const float4*)in)[2 * i + 1];
    short8 o;
    o[0] = bfc(a.x); o[1] = bfc(a.y); o[2] = bfc(a.z); o[3] = bfc(a.w);
    o[4] = bfc(b.x); o[5] = bfc(b.y); o[6] = bfc(b.z); o[7] = bfc(b.w);
    ((short8*)out)[i] = o;
  }
}

// ---------------- all-bf16 GEMM: C = A * B^T, BM x 128 tile, BK=64 ----------
template<int BF16OUT, int VSPLIT, int BM>
__global__ __launch_bounds__(256, 2)
void gemm_bb(const short* __restrict__ A, const short* __restrict__ B,
             void* __restrict__ Cv, short* __restrict__ vtb,
             int M, int N, int K, int lda, int ldb, int ldc) {
  constexpr int MR = BM / 32;
  constexpr int ACH = BM / 32;
  alignas(16) __shared__ short sA[BM * 64];
  alignas(16) __shared__ short sB[128 * 64];
  const int tid = threadIdx.x;
  const int w = tid >> 6, l = tid & 63;
  const int lg = l >> 4, lr = l & 15;
  const int brow = blockIdx.y * BM, bcol = blockIdx.x * 128;
  const int wr = (w >> 1) * (BM / 2), wc = (w & 1) * 64;

  f32x4 acc[MR][4];
  #pragma unroll
  for (int m = 0; m < MR; ++m)
    #pragma unroll
    for (int n = 0; n < 4; ++n)
      acc[m][n] = (f32x4){0.f, 0.f, 0.f, 0.f};

  const short* gA[ACH]; short* lA[ACH];
  #pragma unroll
  for (int j = 0; j < ACH; ++j) {
    int c = w * ACH + j;
    int row = c * 8 + (l >> 3);
    int sb = ((l & 7) * 16) ^ ((row & 7) << 4);
    gA[j] = A + (size_t)(brow + row) * lda + sb / 2;
    lA[j] = sA + c * 512;
  }
  const short* gB[4]; short* lB[4];
  #pragma unroll
  for (int j = 0; j < 4; ++j) {
    int c = w * 4 + j;
    int row = c * 8 + (l >> 3);
    int sb = ((l & 7) * 16) ^ ((row & 7) << 4);
    gB[j] = B + (size_t)(bcol + row) * ldb + sb / 2;
    lB[j] = sB + c * 512;
  }

  for (int k0 = 0; k0 < K; k0 += 64) {
    #pragma unroll
    for (int j = 0; j < ACH; ++j) gll16(gA[j] + k0, lA[j]);
    #pragma unroll
    for (int j = 0; j < 4; ++j) gll16(gB[j] + k0, lB[j]);
    __syncthreads();

    #pragma unroll
    for (int kk = 0; kk < 2; ++kk) {
      short8 af[MR], bfr[4];
      #pragma unroll
      for (int m = 0; m < MR; ++m) {
        int ra = wr + m * 16 + lr;
        af[m] = *(const short8*)((const char*)sA + ra * 128 + ((kk * 64 + lg * 16) ^ ((ra & 7) << 4)));
      }
      #pragma unroll
      for (int n = 0; n < 4; ++n) {
        int rb = wc + n * 16 + lr;
        bfr[n] = *(const short8*)((const char*)sB + rb * 128 + ((kk * 64 + lg * 16) ^ ((rb & 7) << 4)));
      }
      #pragma unroll
      for (int m = 0; m < MR; ++m)
        #pragma unroll
        for (int n = 0; n < 4; ++n)
          acc[m][n] = __builtin_amdgcn_mfma_f32_16x16x32_bf16(af[m], bfr[n], acc[m][n], 0, 0, 0);
    }
    __syncthreads();
  }

  const bool vpart = VSPLIT && (bcol >= 4096);
  #pragma unroll
  for (int m = 0; m < MR; ++m)
    #pragma unroll
    for (int n = 0; n < 4; ++n) {
      if (vpart) {
        int d = bcol + wc + n * 16 + lr - 4096;
        int t0 = brow + wr + m * 16 + lg * 4;
        short4_t pk;
        pk[0] = bfc(acc[m][n][0]); pk[1] = bfc(acc[m][n][1]);
        pk[2] = bfc(acc[m][n][2]); pk[3] = bfc(acc[m][n][3]);
        *(short4_t*)(vtb + (size_t)d * 2048 + t0) = pk;
      } else {
        #pragma unroll
        for (int j = 0; j < 4; ++j) {
          size_t idx = (size_t)(brow + wr + m * 16 + lg * 4 + j) * ldc + (bcol + wc + n * 16 + lr);
          if (BF16OUT) ((short*)Cv)[idx] = bfc(acc[m][n][j]);
          else         ((float*)Cv)[idx] = acc[m][n][j];
        }
      }
    }
}

// ---------------- causal flash attention (split-KV, V in registers) --------
// qkv: [2048][6144] bf16 (Q|K|_). vt: [2048 d][2048 t] bf16 (V^T).
// Each (h, qb) task split into 2 blocks covering half the kv range.
// Partials (unnormalized y_s bf16 + m_s/l_s f32) combined by attn_combine.
// LDS: K double-buffer (32 KB) + P (9 KB) = 41984 B -> 3 blocks/CU.
__global__ __launch_bounds__(256, 3)
void attn_fwd(const short* __restrict__ qkv, const short* __restrict__ vt,
              short* __restrict__ y0b, short* __restrict__ y1b,
              float* __restrict__ ml) {
  constexpr int LDQ = 6144;
  const int h = blockIdx.x;                       // x-fastest: LPT over heads
  const int qb = 31 - ((int)blockIdx.y >> 1);     // longest q-blocks dispatched first
  const int sid = blockIdx.y & 1;
  const int tid = threadIdx.x;
  const int w = tid >> 6, l = tid & 63;
  const int lg = l >> 4, lr = l & 15;
  const f32x4 fzero = {0.f, 0.f, 0.f, 0.f};

  alignas(16) __shared__ short sK[2][64 * 128];   // 256B rows, XOR ((row&7)<<4)
  alignas(16) __shared__ short sP[4][16][72];     // per-wave P, row stride 144B

  const int nkb = qb + 1, half = (nkb + 1) >> 1;
  const int kb0 = sid ? half : 0, kb1 = sid ? nkb : half;

  const int qrow0 = qb * 64 + w * 16;
  short8 qf[4];
  #pragma unroll
  for (int kk = 0; kk < 4; ++kk)
    qf[kk] = *(const short8*)(qkv + (size_t)(qrow0 + lr) * LDQ + h * 128 + kk * 32 + lg * 8);

  float m_run[4] = {-1e30f, -1e30f, -1e30f, -1e30f};
  float l_run[4] = {0.f, 0.f, 0.f, 0.f};
  f32x4 yacc[8];
  #pragma unroll
  for (int dt = 0; dt < 8; ++dt) yacc[dt] = fzero;

  // K staging: chunk c = w*4+j -> lane l writes LDS byte c*1024 + l*16
  const short* gK[4]; int loff[4];
  #pragma unroll
  for (int j = 0; j < 4; ++j) {
    int c = w * 4 + j;
    loff[j] = c * 1024 + l * 16;
    int rk = c * 4 + (l >> 4);
    int sbk = ((l & 15) * 16) ^ ((rk & 7) << 4);
    gK[j] = qkv + (size_t)rk * LDQ + 2048 + h * 128 + sbk / 2;
  }
  // V fragment per-lane base: d-row = h*128 + dt*16 + lr, t offset lg*8
  const short* vrow = vt + (size_t)(h * 128 + lr) * 2048 + lg * 8;

  const float scale = 0.088388347648318447f;   // 1/sqrt(128)

  // prologue: stage K tile kb0 into buffer 0
  {
    const size_t koff = (size_t)kb0 * 64 * LDQ;
    #pragma unroll
    for (int j = 0; j < 4; ++j) gll16(gK[j] + koff, (char*)sK[0] + loff[j]);
  }

  for (int kb = kb0; kb < kb1; ++kb) {
    const int cur = (kb - kb0) & 1;
    __syncthreads();                  // K tile kb landed; prev reads of buf cur^1 done

    // V tile kb -> registers (issued first so PV's waitcnt doesn't drain K prefetch)
    short8 vf[8][2];
    const int kvo = kb * 64;
    #pragma unroll
    for (int dt = 0; dt < 8; ++dt)
      #pragma unroll
      for (int ks = 0; ks < 2; ++ks)
        vf[dt][ks] = *(const short8*)(vrow + (size_t)dt * 32768 + kvo + ks * 32);
    // K prefetch tile kb+1
    if (kb + 1 < kb1) {
      const size_t koff = (size_t)(kb + 1) * 64 * LDQ;
      #pragma unroll
      for (int j = 0; j < 4; ++j) gll16(gK[j] + koff, (char*)sK[cur ^ 1] + loff[j]);
    }
    __builtin_amdgcn_sched_barrier(0);   // pin load issue before compute

    // S = Q K^T  (16x64 per wave)
    f32x4 st[4];
    __builtin_amdgcn_s_setprio(1);
    #pragma unroll
    for (int ct = 0; ct < 4; ++ct) {
      f32x4 a = fzero;
      int row = ct * 16 + lr;
      #pragma unroll
      for (int kk = 0; kk < 4; ++kk) {
        int cb = (kk * 64 + lg * 16) ^ ((row & 7) << 4);
        short8 kf = *(const short8*)((const char*)sK[cur] + row * 256 + cb);
        a = __builtin_amdgcn_mfma_f32_16x16x32_bf16(qf[kk], kf, a, 0, 0, 0);
      }
      st[ct] = a;
    }
    __builtin_amdgcn_s_setprio(0);

    // online softmax (row = lg*4+j, col = lr within 16-lane group)
    const bool diag = (kb == qb);
    float p[4][4];
    #pragma unroll
    for (int j = 0; j < 4; ++j) {
      const int grow = qrow0 + lg * 4 + j;
      float mx = -1e30f;
      #pragma unroll
      for (int ct = 0; ct < 4; ++ct) {
        float sv = st[ct][j] * scale;
        if (diag && (kb * 64 + ct * 16 + lr > grow)) sv = -1e30f;
        p[j][ct] = sv;
        mx = fmaxf(mx, sv);
      }
      #pragma unroll
      for (int off = 1; off < 16; off <<= 1) mx = fmaxf(mx, __shfl_xor(mx, off));
      if (__any(mx > m_run[j] + 8.f)) {            // defer-max (T13)
        float mnew = fmaxf(m_run[j], mx);
        float sc = __expf(m_run[j] - mnew);
        m_run[j] = mnew;
        l_run[j] *= sc;
        #pragma unroll
        for (int dt = 0; dt < 8; ++dt) yacc[dt][j] *= sc;
      }
      float sum = 0.f;
      #pragma unroll
      for (int ct = 0; ct < 4; ++ct) { float e = __expf(p[j][ct] - m_run[j]); p[j][ct] = e; sum += e; }
      #pragma unroll
      for (int off = 1; off < 16; off <<= 1) sum += __shfl_xor(sum, off);
      l_run[j] += sum;
    }

    // P -> LDS (wave-synchronous)
    #pragma unroll
    for (int j = 0; j < 4; ++j)
      #pragma unroll
      for (int ct = 0; ct < 4; ++ct)
        sP[w][lg * 4 + j][ct * 16 + lr] = bfc(p[j][ct]);
    asm volatile("s_waitcnt lgkmcnt(0)" ::: "memory");
    __builtin_amdgcn_sched_barrier(0);

    // y += P V   (V from registers)
    __builtin_amdgcn_s_setprio(1);
    #pragma unroll
    for (int dt = 0; dt < 8; ++dt) {
      #pragma unroll
      for (int ks = 0; ks < 2; ++ks) {
        short8 pa = *(const short8*)(&sP[w][lr][ks * 32 + lg * 8]);
        yacc[dt] = __builtin_amdgcn_mfma_f32_16x16x32_bf16(pa, vf[dt][ks], yacc[dt], 0, 0, 0);
      }
    }
    __builtin_amdgcn_s_setprio(0);
  }

  // epilogue: write UNNORMALIZED partial + (m, l)
  #pragma unroll
  for (int j = 0; j < 4; ++j) {
    int grow = qrow0 + lg * 4 + j;
    if (sid == 0) {
      #pragma unroll
      for (int dt = 0; dt < 8; ++dt)
        y0b[(size_t)grow * LDQ + 4096 + h * 128 + dt * 16 + lr] = bfc(yacc[dt][j]);
    } else {
      #pragma unroll
      for (int dt = 0; dt < 8; ++dt)
        y1b[(size_t)grow * 2048 + h * 128 + dt * 16 + lr] = bfc(yacc[dt][j]);
    }
    if (lr == 0) {
      ml[sid * 65536 +         h * 2048 + grow] = m_run[j];
      ml[sid * 65536 + 32768 + h * 2048 + grow] = l_run[j];
    }
  }
}

// ---------------- combine the two KV-half partials ----------------
__global__ __launch_bounds__(256)
void attn_combine(short* __restrict__ y0, const short* __restrict__ y1,
                  const float* __restrict__ ml) {
  int idx = blockIdx.x * 256 + threadIdx.x;        // 524288 total
  int d8  = (idx & 15) * 8;
  int h   = (idx >> 4) & 15;
  int row = idx >> 8;
  int hr  = h * 2048 + row;
  float m0 = ml[hr],          l0 = ml[32768 + hr];
  float m1 = ml[65536 + hr],  l1 = ml[98304 + hr];
  float m  = fmaxf(m0, m1);
  float e0 = __expf(m0 - m),  e1 = __expf(m1 - m);
  float inv = 1.f / (e0 * l0 + e1 * l1);
  float s0 = e0 * inv, s1 = e1 * inv;
  short* p0 = y0 + (size_t)row * 6144 + 4096 + h * 128 + d8;
  short8 a = *(const short8*)p0;
  short8 b = *(const short8*)(y1 + (size_t)row * 2048 + h * 128 + d8);
  short8 o;
  #pragma unroll
  for (int e = 0; e < 8; ++e) o[e] = bfc(bf2f(a[e]) * s0 + bf2f(b[e]) * s1);
  *(short8*)p0 = o;
}

// ---------------- launch ----------------
extern "C" void kernel_launch(void* const* d_in, const int* in_sizes, int n_in,
                              void* d_out, int out_size, void* d_ws, size_t ws_size,
                              hipStream_t stream) {
  const float* x      = (const float*)d_in[0];
  const float* w_attn = (const float*)d_in[1];
  const float* w_proj = (const float*)d_in[2];
  float* out = (float*)d_out;
  char* ws = (char*)d_ws;

  // ws (72 MiB, proven available in round 7):
  //   qkvb 24 MiB | vtb 8 MiB | xb 8 MiB | wab 24 MiB | wpb 8 MiB
  // After GEMM1, xb holds the y1 attention partial and wab's first 512 KB
  // holds the m/l partials (both dead as GEMM inputs by then).
  short* qkvb = (short*)(ws);
  short* vtb  = (short*)(ws + 25165824);
  short* xb   = (short*)(ws + 33554432);
  short* wab  = (short*)(ws + 41943040);
  short* wpb  = (short*)(ws + 67108864);

  cvt_bf16<<<dim3(2048), dim3(256), 0, stream>>>(x,      xb,   524288);
  cvt_bf16<<<dim3(2048), dim3(256), 0, stream>>>(w_attn, wab, 1572864);
  cvt_bf16<<<dim3(2048), dim3(256), 0, stream>>>(w_proj, wpb,  524288);

  // qkv = x @ w_attn^T; V part written transposed into vtb
  gemm_bb<1, 1, 128><<<dim3(48, 16), dim3(256), 0, stream>>>(
      xb, wab, (void*)qkvb, vtb, 2048, 6144, 2048, 2048, 2048, 6144);

  // split-KV flash attention: 1024 blocks, partials y0 -> qkvb V region, y1 -> xb
  attn_fwd<<<dim3(16, 64), dim3(256), 0, stream>>>(
      qkvb, vtb, qkvb, xb, (float*)wab);

  attn_combine<<<dim3(2048), dim3(256), 0, stream>>>(qkvb, xb, (const float*)wab);

  // out = y @ w_proj^T
  gemm_bb<0, 0, 64><<<dim3(16, 32), dim3(256), 0, stream>>>(
      qkvb + 4096, wpb, (void*)out, nullptr, 2048, 2048, 2048, 6144, 2048, 2048);
}

// Round 9
// 260.051 us; speedup vs baseline: 1.7844x; 1.7844x over previous
//
#include <hip/hip_runtime.h>
#include <hip/hip_bf16.h>

typedef __attribute__((ext_vector_type(8))) short short8;
typedef __attribute__((ext_vector_type(4))) short short4_t;
typedef __attribute__((ext_vector_type(4))) float f32x4;

__device__ __forceinline__ short bfc(float f) {
  return __builtin_bit_cast(short, __float2bfloat16(f));
}
__device__ __forceinline__ float bf2f(short s) {
  unsigned u = ((unsigned)(unsigned short)s) << 16;
  return __builtin_bit_cast(float, u);
}

__device__ __forceinline__ void gll16(const void* g, void* l) {
  __builtin_amdgcn_global_load_lds((const __attribute__((address_space(1))) unsigned int*)g,
                                   (__attribute__((address_space(3))) unsigned int*)l,
                                   16, 0, 0);
}

// ---------------- fp32 -> bf16 convert ----------------
__global__ void cvt_bf16(const float* __restrict__ in, short* __restrict__ out, int n8) {
  int i = blockIdx.x * blockDim.x + threadIdx.x;
  int stride = gridDim.x * blockDim.x;
  for (; i < n8; i += stride) {
    float4 a = ((const float4*)in)[2 * i];
    float4 b = ((const float4*)in)[2 * i + 1];
    short8 o;
    o[0] = bfc(a.x); o[1] = bfc(a.y); o[2] = bfc(a.z); o[3] = bfc(a.w);
    o[4] = bfc(b.x); o[5] = bfc(b.y); o[6] = bfc(b.z); o[7] = bfc(b.w);
    ((short8*)out)[i] = o;
  }
}

// ---------------- all-bf16 GEMM: C = A * B^T, BM x 128 tile, BK=64 ----------
template<int BF16OUT, int VSPLIT, int BM>
__global__ __launch_bounds__(256, 2)
void gemm_bb(const short* __restrict__ A, const short* __restrict__ B,
             void* __restrict__ Cv, short* __restrict__ vtb,
             int M, int N, int K, int lda, int ldb, int ldc) {
  constexpr int MR = BM / 32;
  constexpr int ACH = BM / 32;
  alignas(16) __shared__ short sA[BM * 64];
  alignas(16) __shared__ short sB[128 * 64];
  const int tid = threadIdx.x;
  const int w = tid >> 6, l = tid & 63;
  const int lg = l >> 4, lr = l & 15;
  const int brow = blockIdx.y * BM, bcol = blockIdx.x * 128;
  const int wr = (w >> 1) * (BM / 2), wc = (w & 1) * 64;

  f32x4 acc[MR][4];
  #pragma unroll
  for (int m = 0; m < MR; ++m)
    #pragma unroll
    for (int n = 0; n < 4; ++n)
      acc[m][n] = (f32x4){0.f, 0.f, 0.f, 0.f};

  const short* gA[ACH]; short* lA[ACH];
  #pragma unroll
  for (int j = 0; j < ACH; ++j) {
    int c = w * ACH + j;
    int row = c * 8 + (l >> 3);
    int sb = ((l & 7) * 16) ^ ((row & 7) << 4);
    gA[j] = A + (size_t)(brow + row) * lda + sb / 2;
    lA[j] = sA + c * 512;
  }
  const short* gB[4]; short* lB[4];
  #pragma unroll
  for (int j = 0; j < 4; ++j) {
    int c = w * 4 + j;
    int row = c * 8 + (l >> 3);
    int sb = ((l & 7) * 16) ^ ((row & 7) << 4);
    gB[j] = B + (size_t)(bcol + row) * ldb + sb / 2;
    lB[j] = sB + c * 512;
  }

  for (int k0 = 0; k0 < K; k0 += 64) {
    #pragma unroll
    for (int j = 0; j < ACH; ++j) gll16(gA[j] + k0, lA[j]);
    #pragma unroll
    for (int j = 0; j < 4; ++j) gll16(gB[j] + k0, lB[j]);
    __syncthreads();

    #pragma unroll
    for (int kk = 0; kk < 2; ++kk) {
      short8 af[MR], bfr[4];
      #pragma unroll
      for (int m = 0; m < MR; ++m) {
        int ra = wr + m * 16 + lr;
        af[m] = *(const short8*)((const char*)sA + ra * 128 + ((kk * 64 + lg * 16) ^ ((ra & 7) << 4)));
      }
      #pragma unroll
      for (int n = 0; n < 4; ++n) {
        int rb = wc + n * 16 + lr;
        bfr[n] = *(const short8*)((const char*)sB + rb * 128 + ((kk * 64 + lg * 16) ^ ((rb & 7) << 4)));
      }
      #pragma unroll
      for (int m = 0; m < MR; ++m)
        #pragma unroll
        for (int n = 0; n < 4; ++n)
          acc[m][n] = __builtin_amdgcn_mfma_f32_16x16x32_bf16(af[m], bfr[n], acc[m][n], 0, 0, 0);
    }
    __syncthreads();
  }

  const bool vpart = VSPLIT && (bcol >= 4096);
  #pragma unroll
  for (int m = 0; m < MR; ++m)
    #pragma unroll
    for (int n = 0; n < 4; ++n) {
      if (vpart) {
        int d = bcol + wc + n * 16 + lr - 4096;
        int t0 = brow + wr + m * 16 + lg * 4;
        short4_t pk;
        pk[0] = bfc(acc[m][n][0]); pk[1] = bfc(acc[m][n][1]);
        pk[2] = bfc(acc[m][n][2]); pk[3] = bfc(acc[m][n][3]);
        *(short4_t*)(vtb + (size_t)d * 2048 + t0) = pk;
      } else {
        #pragma unroll
        for (int j = 0; j < 4; ++j) {
          size_t idx = (size_t)(brow + wr + m * 16 + lg * 4 + j) * ldc + (bcol + wc + n * 16 + lr);
          if (BF16OUT) ((short*)Cv)[idx] = bfc(acc[m][n][j]);
          else         ((float*)Cv)[idx] = acc[m][n][j];
        }
      }
    }
}

// ---------------- causal flash attention (split-KV, V in LDS) --------------
// qkv: [2048][6144] bf16 (Q|K|_). vt: [2048 d][2048 t] bf16 (V^T).
// Each (h, qb) task split into 2 blocks covering half the kv range; partials
// (unnormalized y_s bf16 + m_s/l_s f32) combined by attn_combine.
// Grid (16 heads, 64 tasks): XCD = head%8 (K/V L2 affinity), y-order = LPT.
// LDS: K dbuf 32K + V^T dbuf 32K + P 9K = 73KB -> 2 blocks/CU, VGPR ~100.
__global__ __launch_bounds__(256, 2)
void attn_fwd(const short* __restrict__ qkv, const short* __restrict__ vt,
              short* __restrict__ y0b, short* __restrict__ y1b,
              float* __restrict__ ml) {
  constexpr int LDQ = 6144;
  const int h = blockIdx.x;
  const int qb = 31 - ((int)blockIdx.y >> 1);     // longest tasks first
  const int sid = blockIdx.y & 1;
  const int tid = threadIdx.x;
  const int w = tid >> 6, l = tid & 63;
  const int lg = l >> 4, lr = l & 15;
  const f32x4 fzero = {0.f, 0.f, 0.f, 0.f};

  alignas(16) __shared__ short sK[2][64 * 128];   // 256B rows, XOR ((row&7)<<4)
  alignas(16) __shared__ short sVt[2][128 * 64];  // [d][kv] 128B rows, XOR ((d&7)<<4)
  alignas(16) __shared__ short sP[4][16][72];     // per-wave P, row stride 144B

  const int nkb = qb + 1, half = (nkb + 1) >> 1;
  const int kb0 = sid ? half : 0, kb1 = sid ? nkb : half;

  const int qrow0 = qb * 64 + w * 16;
  short8 qf[4];
  #pragma unroll
  for (int kk = 0; kk < 4; ++kk)
    qf[kk] = *(const short8*)(qkv + (size_t)(qrow0 + lr) * LDQ + h * 128 + kk * 32 + lg * 8);

  float m_run[4] = {-1e30f, -1e30f, -1e30f, -1e30f};
  float l_run[4] = {0.f, 0.f, 0.f, 0.f};
  f32x4 yacc[8];
  #pragma unroll
  for (int dt = 0; dt < 8; ++dt) yacc[dt] = fzero;

  // staging: per wave 4 K chunks + 4 V chunks; LDS byte = c*1024 + l*16
  const short* gK[4]; const short* gV[4]; int loff[4];
  #pragma unroll
  for (int j = 0; j < 4; ++j) {
    int c = w * 4 + j;
    loff[j] = c * 1024 + l * 16;
    int rk = c * 4 + (l >> 4);                      // K row (kv)
    int sbk = ((l & 15) * 16) ^ ((rk & 7) << 4);
    gK[j] = qkv + (size_t)rk * LDQ + 2048 + h * 128 + sbk / 2;
    int rv = c * 8 + (l >> 3);                      // V^T row (d)
    int sbv = ((l & 7) * 16) ^ (((l >> 3) & 7) << 4);
    gV[j] = vt + (size_t)(h * 128 + rv) * 2048 + sbv / 2;
  }

  const float scale = 0.088388347648318447f;   // 1/sqrt(128)

  // prologue: stage tile kb0 into buffer 0
  {
    const size_t koff = (size_t)kb0 * 64 * LDQ;
    const int voff = kb0 * 64;
    #pragma unroll
    for (int j = 0; j < 4; ++j) {
      gll16(gK[j] + koff, (char*)sK[0] + loff[j]);
      gll16(gV[j] + voff, (char*)sVt[0] + loff[j]);
    }
  }

  for (int kb = kb0; kb < kb1; ++kb) {
    const int cur = (kb - kb0) & 1;
    __syncthreads();                  // tile kb landed; prev reads of buf cur^1 done

    if (kb + 1 < kb1) {               // prefetch tile kb+1, covered by compute
      const size_t koff = (size_t)(kb + 1) * 64 * LDQ;
      const int voff = (kb + 1) * 64;
      #pragma unroll
      for (int j = 0; j < 4; ++j) {
        gll16(gK[j] + koff, (char*)sK[cur ^ 1] + loff[j]);
        gll16(gV[j] + voff, (char*)sVt[cur ^ 1] + loff[j]);
      }
    }

    // S = Q K^T  (16x64 per wave)
    f32x4 st[4];
    __builtin_amdgcn_s_setprio(1);
    #pragma unroll
    for (int ct = 0; ct < 4; ++ct) {
      f32x4 a = fzero;
      int row = ct * 16 + lr;
      #pragma unroll
      for (int kk = 0; kk < 4; ++kk) {
        int cb = (kk * 64 + lg * 16) ^ ((row & 7) << 4);
        short8 kf = *(const short8*)((const char*)sK[cur] + row * 256 + cb);
        a = __builtin_amdgcn_mfma_f32_16x16x32_bf16(qf[kk], kf, a, 0, 0, 0);
      }
      st[ct] = a;
    }
    __builtin_amdgcn_s_setprio(0);

    // online softmax (row = lg*4+j, col = lr within 16-lane group)
    const bool diag = (kb == qb);
    float p[4][4];
    #pragma unroll
    for (int j = 0; j < 4; ++j) {
      const int grow = qrow0 + lg * 4 + j;
      float mx = -1e30f;
      #pragma unroll
      for (int ct = 0; ct < 4; ++ct) {
        float sv = st[ct][j] * scale;
        if (diag && (kb * 64 + ct * 16 + lr > grow)) sv = -1e30f;
        p[j][ct] = sv;
        mx = fmaxf(mx, sv);
      }
      #pragma unroll
      for (int off = 1; off < 16; off <<= 1) mx = fmaxf(mx, __shfl_xor(mx, off));
      if (__any(mx > m_run[j] + 8.f)) {            // defer-max (T13)
        float mnew = fmaxf(m_run[j], mx);
        float sc = __expf(m_run[j] - mnew);
        m_run[j] = mnew;
        l_run[j] *= sc;
        #pragma unroll
        for (int dt = 0; dt < 8; ++dt) yacc[dt][j] *= sc;
      }
      float sum = 0.f;
      #pragma unroll
      for (int ct = 0; ct < 4; ++ct) { float e = __expf(p[j][ct] - m_run[j]); p[j][ct] = e; sum += e; }
      #pragma unroll
      for (int off = 1; off < 16; off <<= 1) sum += __shfl_xor(sum, off);
      l_run[j] += sum;
    }

    // P -> LDS (wave-synchronous)
    #pragma unroll
    for (int j = 0; j < 4; ++j)
      #pragma unroll
      for (int ct = 0; ct < 4; ++ct)
        sP[w][lg * 4 + j][ct * 16 + lr] = bfc(p[j][ct]);
    asm volatile("s_waitcnt lgkmcnt(0)" ::: "memory");
    __builtin_amdgcn_sched_barrier(0);

    // y += P V  (B-fragment from sVt[d][kv])
    __builtin_amdgcn_s_setprio(1);
    #pragma unroll
    for (int dt = 0; dt < 8; ++dt) {
      int d = dt * 16 + lr;
      #pragma unroll
      for (int ks = 0; ks < 2; ++ks) {
        short8 pa = *(const short8*)(&sP[w][lr][ks * 32 + lg * 8]);
        int cb = (ks * 64 + lg * 16) ^ ((d & 7) << 4);
        short8 vf = *(const short8*)((const char*)sVt[cur] + d * 128 + cb);
        yacc[dt] = __builtin_amdgcn_mfma_f32_16x16x32_bf16(pa, vf, yacc[dt], 0, 0, 0);
      }
    }
    __builtin_amdgcn_s_setprio(0);
  }

  // epilogue: write UNNORMALIZED partial + (m, l)
  #pragma unroll
  for (int j = 0; j < 4; ++j) {
    int grow = qrow0 + lg * 4 + j;
    if (sid == 0) {
      #pragma unroll
      for (int dt = 0; dt < 8; ++dt)
        y0b[(size_t)grow * LDQ + 4096 + h * 128 + dt * 16 + lr] = bfc(yacc[dt][j]);
    } else {
      #pragma unroll
      for (int dt = 0; dt < 8; ++dt)
        y1b[(size_t)grow * 2048 + h * 128 + dt * 16 + lr] = bfc(yacc[dt][j]);
    }
    if (lr == 0) {
      ml[sid * 65536 +         h * 2048 + grow] = m_run[j];
      ml[sid * 65536 + 32768 + h * 2048 + grow] = l_run[j];
    }
  }
}

// ---------------- combine the two KV-half partials ----------------
__global__ __launch_bounds__(256)
void attn_combine(short* __restrict__ y0, const short* __restrict__ y1,
                  const float* __restrict__ ml) {
  int idx = blockIdx.x * 256 + threadIdx.x;        // 524288 total
  int d8  = (idx & 15) * 8;
  int h   = (idx >> 4) & 15;
  int row = idx >> 8;
  int hr  = h * 2048 + row;
  float m0 = ml[hr],          l0 = ml[32768 + hr];
  float m1 = ml[65536 + hr],  l1 = ml[98304 + hr];
  float m  = fmaxf(m0, m1);
  float e0 = __expf(m0 - m),  e1 = __expf(m1 - m);
  float inv = 1.f / (e0 * l0 + e1 * l1);
  float s0 = e0 * inv, s1 = e1 * inv;
  short* p0 = y0 + (size_t)row * 6144 + 4096 + h * 128 + d8;
  short8 a = *(const short8*)p0;
  short8 b = *(const short8*)(y1 + (size_t)row * 2048 + h * 128 + d8);
  short8 o;
  #pragma unroll
  for (int e = 0; e < 8; ++e) o[e] = bfc(bf2f(a[e]) * s0 + bf2f(b[e]) * s1);
  *(short8*)p0 = o;
}

// ---------------- launch ----------------
extern "C" void kernel_launch(void* const* d_in, const int* in_sizes, int n_in,
                              void* d_out, int out_size, void* d_ws, size_t ws_size,
                              hipStream_t stream) {
  const float* x      = (const float*)d_in[0];
  const float* w_attn = (const float*)d_in[1];
  const float* w_proj = (const float*)d_in[2];
  float* out = (float*)d_out;
  char* ws = (char*)d_ws;

  // ws (72 MiB): qkvb 24 | vtb 8 | xb 8 | wab 24 | wpb 8
  // After GEMM1, xb holds the y1 attention partial; wab's first 512 KB holds
  // the m/l partials (both dead as GEMM inputs by then).
  short* qkvb = (short*)(ws);
  short* vtb  = (short*)(ws + 25165824);
  short* xb   = (short*)(ws + 33554432);
  short* wab  = (short*)(ws + 41943040);
  short* wpb  = (short*)(ws + 67108864);

  cvt_bf16<<<dim3(2048), dim3(256), 0, stream>>>(x,      xb,   524288);
  cvt_bf16<<<dim3(2048), dim3(256), 0, stream>>>(w_attn, wab, 1572864);
  cvt_bf16<<<dim3(2048), dim3(256), 0, stream>>>(w_proj, wpb,  524288);

  // qkv = x @ w_attn^T; V part written transposed into vtb
  gemm_bb<1, 1, 128><<<dim3(48, 16), dim3(256), 0, stream>>>(
      xb, wab, (void*)qkvb, vtb, 2048, 6144, 2048, 2048, 2048, 6144);

  // split-KV flash attention: 1024 blocks; y0 -> qkvb V region, y1 -> xb
  attn_fwd<<<dim3(16, 64), dim3(256), 0, stream>>>(
      qkvb, vtb, qkvb, xb, (float*)wab);

  attn_combine<<<dim3(2048), dim3(256), 0, stream>>>(qkvb, xb, (const float*)wab);

  // out = y @ w_proj^T
  gemm_bb<0, 0, 64><<<dim3(16, 32), dim3(256), 0, stream>>>(
      qkvb + 4096, wpb, (void*)out, nullptr, 2048, 2048, 2048, 6144, 2048, 2048);
}